// Round 1
// 222.232 us; speedup vs baseline: 1.0453x; 1.0453x over previous
//
#include <hip/hip_runtime.h>

// Problem constants (from reference setup_inputs)
#define BB  16
#define LL  100
#define LOC 2000
#define EE  16

// SU=500, SL=0, TU=3600, TL=0
// out[b,l,j,e] = base[e] + coef[e] * ds[j]
//   base[e] = esl[m,e] + etl[m,e]*(1-wt) + etu[m,e]*wt,  wt = vec[b,l]/3600
//   coef[e] = (esu[m,e]-esl[m,e]) / 500
//   ds[j]   = valid ? mat2[row, j] : 0
__global__ __launch_bounds__(256) void embed_kernel(
    const int*   __restrict__ traj_loc,   // (B,L)
    const float* __restrict__ mat2,       // (LOC,LOC)
    const float* __restrict__ vec,        // (B,L)
    const int*   __restrict__ traj_len,   // (B,)
    const float* __restrict__ emb_sl,     // (2,E)
    const float* __restrict__ emb_su,     // (2,E)
    const float* __restrict__ emb_tl,     // (2,E)
    const float* __restrict__ emb_tu,     // (2,E)
    float*       __restrict__ out)        // (B,L,LOC,E)
{
    const int bl = blockIdx.x;            // 0 .. B*L-1
    const int b  = bl / LL;
    const int l  = bl - b * LL;

    const bool valid = l < traj_len[b];
    const int  m     = valid ? 1 : 0;

    int row = traj_loc[bl] - 1;
    row = min(max(row, 0), LOC - 1);

    const float dt = vec[bl];
    const float wt = dt * (1.0f / 3600.0f);   // dt/(TU-TL)

    const int tid = threadIdx.x;
    const int e0  = (tid & 3) * 4;            // this thread's 4 consecutive e's
    const int j0  = tid >> 2;                 // 0..63  (j lane)

    // Per-(b,l) constants: out[j,e] = base[e] + coef[e] * ds[j]
    float base[4], coef[4];
    #pragma unroll
    for (int k = 0; k < 4; ++k) {
        const int e  = e0 + k;
        const float sl = emb_sl[m * EE + e];
        const float su = emb_su[m * EE + e];
        const float tl = emb_tl[m * EE + e];
        const float tu = emb_tu[m * EE + e];
        base[k] = sl + tl * (1.0f - wt) + tu * wt;
        coef[k] = (su - sl) * (1.0f / 500.0f); // /(SU-SL)
    }

    const float* __restrict__ rowp = mat2 + (size_t)row * LOC;
    float*       __restrict__ outp = out  + (size_t)bl * LOC * EE;

    // ---- Phase 1: preload ALL ds values for this thread into registers. ----
    // j = j0 + 64*i covers [0,2048); i=0..30 always in-bounds (max j = 63+1920
    // = 1983 < 2000); i=31 in-bounds iff j0 < 16 (j = j0+1984 <= 1999).
    // Fully unrolled => static indexing => stays in VGPRs (no scratch).
    float ds[32];
    if (valid) {
        #pragma unroll
        for (int i = 0; i < 31; ++i) {
            ds[i] = rowp[j0 + 64 * i];
        }
        ds[31] = (j0 < 16) ? rowp[j0 + 64 * 31] : 0.0f;
    } else {
        #pragma unroll
        for (int i = 0; i < 32; ++i) ds[i] = 0.0f;
    }

    // ---- Phase 2: pure store stream — NO VMEM loads in this loop, so the
    // compiler never has to wait on vmcnt here; stores stay in flight like a
    // memset instead of being fenced each iteration by the ds load wait. ----
    #pragma unroll
    for (int i = 0; i < 31; ++i) {
        const int j = j0 + 64 * i;
        float4 v;
        v.x = base[0] + coef[0] * ds[i];
        v.y = base[1] + coef[1] * ds[i];
        v.z = base[2] + coef[2] * ds[i];
        v.w = base[3] + coef[3] * ds[i];
        *reinterpret_cast<float4*>(outp + (size_t)j * EE + e0) = v;
    }
    if (j0 < 16) {                         // tail: j = j0 + 1984 (<= 1999)
        const int j = j0 + 64 * 31;
        float4 v;
        v.x = base[0] + coef[0] * ds[31];
        v.y = base[1] + coef[1] * ds[31];
        v.z = base[2] + coef[2] * ds[31];
        v.w = base[3] + coef[3] * ds[31];
        *reinterpret_cast<float4*>(outp + (size_t)j * EE + e0) = v;
    }
}

extern "C" void kernel_launch(void* const* d_in, const int* in_sizes, int n_in,
                              void* d_out, int out_size, void* d_ws, size_t ws_size,
                              hipStream_t stream) {
    const int*   traj_loc = (const int*)  d_in[0];
    const float* mat2     = (const float*)d_in[1];
    const float* vec      = (const float*)d_in[2];
    const int*   traj_len = (const int*)  d_in[3];
    const float* emb_sl   = (const float*)d_in[4];
    const float* emb_su   = (const float*)d_in[5];
    const float* emb_tl   = (const float*)d_in[6];
    const float* emb_tu   = (const float*)d_in[7];
    float* out = (float*)d_out;

    embed_kernel<<<BB * LL, 256, 0, stream>>>(
        traj_loc, mat2, vec, traj_len, emb_sl, emb_su, emb_tl, emb_tu, out);
}